// Round 11
// baseline (1609.693 us; speedup 1.0000x reference)
//
#include <hip/hip_runtime.h>
#include <stdint.h>

#define BB 8            // bucket = dst >> 8 (256 dsts per bucket)
#define BSZ 256
#define NBMAX 512       // max buckets per relation (100000>>8 = 391)
#define CAP 6144        // bucket edge capacity (mean ~4096, ~32 sigma margin)

typedef _Float16 half8 __attribute__((ext_vector_type(8)));

// ---------------------------------------------------------------------------
// init: block 0 zeroes bucket cursors; block 1 computes head constants
// (v2l = W2l@Wlin, v2r = W2r@Wlin, cbias = b2.Wlin + blin).
__global__ void kinit(int4* __restrict__ gcur, int n4,
                      const float* __restrict__ W2l, const float* __restrict__ W2r,
                      const float* __restrict__ b2, const float* __restrict__ Wlin,
                      const float* __restrict__ blin, float* __restrict__ hconst) {
    if (blockIdx.x == 0) {
        for (int i = threadIdx.x; i < n4; i += 256) gcur[i] = make_int4(0, 0, 0, 0);
    } else {
        int t = threadIdx.x;
        if (t < 64) {
            const float* W = (t < 32) ? W2l : W2r;
            int k = t & 31;
            float acc = 0.0f;
#pragma unroll
            for (int j = 0; j < 32; j++) acc += W[k * 32 + j] * Wlin[j];
            hconst[t] = acc;
        }
        if (t == 64) {
            float acc = blin[0];
#pragma unroll
            for (int j = 0; j < 32; j++) acc += b2[j] * Wlin[j];
            hconst[64] = acc;
        }
    }
}

// ---------------------------------------------------------------------------
// K1: bin edges into fixed-capacity bucket regions P[b*CAP + slot], slots
// claimed via global atomic cursors. 512 thr x 16 edges = 8192 edges/block
// (longer write runs: ~21 edges/bucket/block). Packed: (src<<8 | dst&255).
__global__ void kbin(const int* __restrict__ e1, const int* __restrict__ e2, int E,
                     int* __restrict__ gcur1, int* __restrict__ gcur2,
                     unsigned int* __restrict__ P1, unsigned int* __restrict__ P2,
                     int blocksPerRel) {
    int rel = blockIdx.x >= blocksPerRel;
    int blk = rel ? blockIdx.x - blocksPerRel : blockIdx.x;
    const int* edge = rel ? e2 : e1;
    int* gcur = rel ? gcur2 : gcur1;
    unsigned int* P = rel ? P2 : P1;
    __shared__ int cnt[NBMAX];
    __shared__ int base[NBMAX];
    for (int i = threadIdx.x; i < NBMAX; i += 512) cnt[i] = 0;
    __syncthreads();
    int cbase = blk * 8192;
    int src[16], dst[16], rk[16];
#pragma unroll
    for (int k = 0; k < 16; k++) {
        int i = cbase + k * 512 + threadIdx.x;
        if (i < E) {
            src[k] = edge[i];
            dst[k] = edge[E + i];
            rk[k] = atomicAdd(&cnt[dst[k] >> BB], 1);
        }
    }
    __syncthreads();
    for (int b = threadIdx.x; b < NBMAX; b += 512)
        base[b] = cnt[b] ? atomicAdd(&gcur[b], cnt[b]) : 0;
    __syncthreads();
#pragma unroll
    for (int k = 0; k < 16; k++) {
        int i = cbase + k * 512 + threadIdx.x;
        if (i < E) {
            int b = dst[k] >> BB;
            int slot = base[b] + rk[k];
            if (slot < CAP)
                P[(size_t)b * CAP + slot] =
                    ((unsigned)src[k] << BB) | (unsigned)(dst[k] & (BSZ - 1));
        }
    }
}

// ---------------------------------------------------------------------------
// K2: per-bucket counting sort in LDS -> sorted srcs (bucket-strided ss)
// + per-node start (ro, absolute into ss) + degree (dg).
__global__ void kbsort(const unsigned int* __restrict__ P1, const unsigned int* __restrict__ P2,
                       const int* __restrict__ gcur1, const int* __restrict__ gcur2,
                       int* __restrict__ ss1, int* __restrict__ ss2,
                       int* __restrict__ ro1, int* __restrict__ ro2,
                       int* __restrict__ dg1, int* __restrict__ dg2,
                       int n1, int n2, int nb1) {
    int rel = blockIdx.x >= nb1;
    int b = rel ? blockIdx.x - nb1 : blockIdx.x;
    const unsigned int* P = (rel ? P2 : P1) + (size_t)b * CAP;
    int m = min((rel ? gcur2 : gcur1)[b], CAP);
    int* ss = (rel ? ss2 : ss1) + (size_t)b * CAP;
    int* ro = rel ? ro2 : ro1;
    int* dg = rel ? dg2 : dg1;
    int N = rel ? n2 : n1;

    __shared__ int cnt[BSZ];
    __shared__ int cur[BSZ];
    __shared__ int wsum[4];
    __shared__ int stage[CAP];

    int d0 = b << BB;
    int nd = min(BSZ, N - d0);
    int tid = threadIdx.x;

    if (tid < BSZ) cnt[tid] = 0;
    __syncthreads();
    for (int i = tid; i < m; i += 512) atomicAdd(&cnt[P[i] & (BSZ - 1)], 1);
    __syncthreads();
    int lane = tid & 63, wid = tid >> 6;
    int v = 0, sc = 0;
    if (tid < BSZ) {
        v = cnt[tid]; sc = v;
#pragma unroll
        for (int off = 1; off < 64; off <<= 1) {
            int t = __shfl_up(sc, off, 64);
            if (lane >= off) sc += t;
        }
        if (lane == 63) wsum[wid] = sc;
    }
    __syncthreads();
    if (tid < BSZ) {
        int woff = 0;
        for (int w = 0; w < wid; w++) woff += wsum[w];
        int excl = woff + sc - v;
        cur[tid] = excl;
        if (tid < nd) {
            ro[d0 + tid] = b * CAP + excl;
            dg[d0 + tid] = v;
        }
    }
    __syncthreads();
    for (int i = tid; i < m; i += 512) {
        unsigned int p = P[i];
        int slot = atomicAdd(&cur[p & (BSZ - 1)], 1);
        stage[slot] = (int)(p >> BB);
    }
    __syncthreads();
    for (int i = tid; i < m; i += 512) ss[i] = stage[i];
}

// ---------------------------------------------------------------------------
// LDS-tiled fused projection: block handles 128 nodes (2 per thread, same od
// group) — halves per-node LDS W-read traffic. y=x@Wy (fp16), s=x@Ws (fp16).
__global__ void proj_tile(
    const float* __restrict__ x1, const float* __restrict__ Wy1, const float* __restrict__ Ws1,
    _Float16* __restrict__ y1, _Float16* __restrict__ s1, int N1, int blocks1,
    const float* __restrict__ x2, const float* __restrict__ Wy2, const float* __restrict__ Ws2,
    _Float16* __restrict__ y2, _Float16* __restrict__ s2, int N2) {
    int rel = blockIdx.x >= blocks1;
    int blk = rel ? blockIdx.x - blocks1 : blockIdx.x;
    const float* x = rel ? x2 : x1;
    const float* Wy = rel ? Wy2 : Wy1;
    const float* Ws = rel ? Ws2 : Ws1;
    _Float16* y = rel ? y2 : y1;
    _Float16* s = rel ? s2 : s1;
    int N = rel ? N2 : N1;

    __shared__ float xs[128][68];     // 34.8 KB
    __shared__ float wyl[64][32];     // 8 KB
    __shared__ float wsl[64][32];     // 8 KB

    int tid = threadIdx.x;
    {
        const float4* a = (const float4*)Wy;
        const float4* b = (const float4*)Ws;
        float4* la = (float4*)&wyl[0][0];
        float4* lb = (float4*)&wsl[0][0];
        la[tid] = a[tid];
        la[tid + 256] = a[tid + 256];
        lb[tid] = b[tid];
        lb[tid + 256] = b[tid + 256];
    }
    int base = blk << 7;
#pragma unroll
    for (int i = 0; i < 8; i++) {
        int idx = i * 256 + tid;            // 0..2047
        int row = idx >> 4, c4 = (idx & 15) << 2;
        int node = base + row;
        float4 v = (node < N) ? *(const float4*)(x + ((size_t)node << 6) + c4)
                              : make_float4(0.f, 0.f, 0.f, 0.f);
        *(float4*)&xs[row][c4] = v;
    }
    __syncthreads();

    int n0 = tid & 63, n1 = n0 + 64;
    int ob = (tid >> 6) << 3;
    float ay0[8] = {0,0,0,0,0,0,0,0}, as0[8] = {0,0,0,0,0,0,0,0};
    float ay1[8] = {0,0,0,0,0,0,0,0}, as1[8] = {0,0,0,0,0,0,0,0};
#pragma unroll
    for (int kc = 0; kc < 16; kc++) {
        float4 xv0 = *(float4*)&xs[n0][kc << 2];
        float4 xv1 = *(float4*)&xs[n1][kc << 2];
#pragma unroll
        for (int kk = 0; kk < 4; kk++) {
            int k = (kc << 2) + kk;
            float x0 = (kk == 0) ? xv0.x : (kk == 1) ? xv0.y : (kk == 2) ? xv0.z : xv0.w;
            float x1v = (kk == 0) ? xv1.x : (kk == 1) ? xv1.y : (kk == 2) ? xv1.z : xv1.w;
            float4 a = *(float4*)&wyl[k][ob];
            float4 b = *(float4*)&wyl[k][ob + 4];
            float4 c = *(float4*)&wsl[k][ob];
            float4 d = *(float4*)&wsl[k][ob + 4];
            ay0[0] += x0 * a.x; ay0[1] += x0 * a.y; ay0[2] += x0 * a.z; ay0[3] += x0 * a.w;
            ay0[4] += x0 * b.x; ay0[5] += x0 * b.y; ay0[6] += x0 * b.z; ay0[7] += x0 * b.w;
            as0[0] += x0 * c.x; as0[1] += x0 * c.y; as0[2] += x0 * c.z; as0[3] += x0 * c.w;
            as0[4] += x0 * d.x; as0[5] += x0 * d.y; as0[6] += x0 * d.z; as0[7] += x0 * d.w;
            ay1[0] += x1v * a.x; ay1[1] += x1v * a.y; ay1[2] += x1v * a.z; ay1[3] += x1v * a.w;
            ay1[4] += x1v * b.x; ay1[5] += x1v * b.y; ay1[6] += x1v * b.z; ay1[7] += x1v * b.w;
            as1[0] += x1v * c.x; as1[1] += x1v * c.y; as1[2] += x1v * c.z; as1[3] += x1v * c.w;
            as1[4] += x1v * d.x; as1[5] += x1v * d.y; as1[6] += x1v * d.z; as1[7] += x1v * d.w;
        }
    }
    int g0 = base + n0, g1 = base + n1;
    if (g0 < N) {
        union { _Float16 h[8]; uint4 v; } uy, us;
#pragma unroll
        for (int j = 0; j < 8; j++) { uy.h[j] = (_Float16)ay0[j]; us.h[j] = (_Float16)as0[j]; }
        *(uint4*)(y + ((size_t)g0 << 5) + ob) = uy.v;
        *(uint4*)(s + ((size_t)g0 << 5) + ob) = us.v;
    }
    if (g1 < N) {
        union { _Float16 h[8]; uint4 v; } uy, us;
#pragma unroll
        for (int j = 0; j < 8; j++) { uy.h[j] = (_Float16)ay1[j]; us.h[j] = (_Float16)as1[j]; }
        *(uint4*)(y + ((size_t)g1 << 5) + ob) = uy.v;
        *(uint4*)(s + ((size_t)g1 << 5) + ob) = us.v;
    }
}

// ---------------------------------------------------------------------------
// merged layer-1 pull (both relations), packed-fp16 accumulation:
// 32-lane group per node; 4 lanes/edge x 16B uint4 (8 fp16), 8 edges/iter,
// half8 acc (v_pk_add_f16), uint4 shuffle reduction. h never materialized:
// tgt[node] = relu(b + s + mean_gather(y)) . v2
__global__ void pull_l1_both(
    const int* __restrict__ ro_p, const int* __restrict__ dg_p, const int* __restrict__ ssp,
    const _Float16* __restrict__ y_c, const _Float16* __restrict__ sp,
    const float* __restrict__ b_p, const float* __restrict__ hconst,
    float* __restrict__ u_p, int NP, int blocksP,
    const int* __restrict__ ro_c, const int* __restrict__ dg_c, const int* __restrict__ ssc,
    const _Float16* __restrict__ y_p, const _Float16* __restrict__ sc_,
    const float* __restrict__ b_c, float* __restrict__ t_c, int NC) {
    int rel = blockIdx.x >= blocksP;
    int blk = rel ? blockIdx.x - blocksP : blockIdx.x;
    const int* ro = rel ? ro_c : ro_p;
    const int* dg = rel ? dg_c : dg_p;
    const int* ss = rel ? ssc : ssp;
    const _Float16* y = rel ? y_p : y_c;
    const _Float16* sf = rel ? sc_ : sp;
    const float* bv = rel ? b_c : b_p;
    const float* v2 = rel ? hconst : hconst + 32;  // t_c:v2l, u_p:v2r
    float* tgt = rel ? t_c : u_p;
    int N = rel ? NC : NP;

    int gid = blk * 256 + threadIdx.x;
    int node = gid >> 5, l = gid & 31;
    if (node >= N) return;
    int el = l >> 2, sub = l & 3;
    int start = ro[node], deg = dg[node];

    union U { uint4 v; half8 h; };
    half8 acc8 = (half8)(_Float16)0;
    for (int base = 0; base < deg; base += 16) {
        int j0 = base + el, j1 = base + 8 + el;
        bool v0 = j0 < deg, v1 = j1 < deg;
        int s0 = v0 ? ss[start + j0] : 0;
        int s1 = v1 ? ss[start + j1] : 0;
        U q0, q1;
        if (v0) q0.v = *(const uint4*)(y + ((size_t)s0 << 5) + (sub << 3));
        if (v1) q1.v = *(const uint4*)(y + ((size_t)s1 << 5) + (sub << 3));
        if (v0) acc8 += q0.h;
        if (v1) acc8 += q1.h;
    }
    // reduce over the 8 edge-lanes (xor 4,8,16) with packed adds
#pragma unroll
    for (int off = 4; off <= 16; off <<= 1) {
        U t, r;
        t.h = acc8;
        r.v.x = __shfl_xor(t.v.x, off, 32);
        r.v.y = __shfl_xor(t.v.y, off, 32);
        r.v.z = __shfl_xor(t.v.z, off, 32);
        r.v.w = __shfl_xor(t.v.w, off, 32);
        acc8 += r.h;
    }

    float invd = 1.0f / fmaxf((float)deg, 1.0f);
    union { uint4 v; _Float16 h[8]; } us;
    us.v = *(const uint4*)(sf + ((size_t)node << 5) + (sub << 3));
    float4 b0 = *(const float4*)(bv + (sub << 3));
    float4 b1 = *(const float4*)(bv + (sub << 3) + 4);
    float4 w0 = *(const float4*)(v2 + (sub << 3));
    float4 w1 = *(const float4*)(v2 + (sub << 3) + 4);
    float bb[8] = {b0.x, b0.y, b0.z, b0.w, b1.x, b1.y, b1.z, b1.w};
    float ww[8] = {w0.x, w0.y, w0.z, w0.w, w1.x, w1.y, w1.z, w1.w};
    float p = 0.0f;
#pragma unroll
    for (int j = 0; j < 8; j++) {
        float r = bb[j] + (float)us.h[j] + (float)acc8[j] * invd;
        p += fmaxf(r, 0.0f) * ww[j];
    }
    p += __shfl_xor(p, 1, 32);
    p += __shfl_xor(p, 2, 32);
    if (l == 0) tgt[node] = p;
}

// ---------------------------------------------------------------------------
// layer-2 scalar pull: logit = mean_{src in N(node)} t_c[src] + u_p[node]+cbias
__global__ void pull_l2_scalar(const int* __restrict__ ro, const int* __restrict__ dg,
                               const int* __restrict__ ss,
                               const float* __restrict__ t_c, const float* __restrict__ u_p,
                               const float* __restrict__ hconst,
                               float* __restrict__ out, int N) {
    int gid = blockIdx.x * blockDim.x + threadIdx.x;
    int node = gid >> 2, ln = gid & 3;
    if (node >= N) return;
    int s = ro[node], deg = dg[node], e = s + deg;
    float acc = 0.0f;
    for (int j = s + ln; j < e; j += 4) acc += t_c[ss[j]];
    acc += __shfl_xor(acc, 1, 4);
    acc += __shfl_xor(acc, 2, 4);
    if (ln == 0) {
        float logit = acc / fmaxf((float)deg, 1.0f) + u_p[node] + hconst[64];
        out[node] = 1.0f / (1.0f + expf(-logit));
    }
}

// ---------------------------------------------------------------------------
extern "C" void kernel_launch(void* const* d_in, const int* in_sizes, int n_in,
                              void* d_out, int out_size, void* d_ws, size_t ws_size,
                              hipStream_t stream) {
    const float* xc    = (const float*)d_in[0];
    const float* xp    = (const float*)d_in[1];
    const int*   e_c2p = (const int*)d_in[2];   // src=cust, dst=prod
    const int*   e_p2c = (const int*)d_in[3];   // src=prod, dst=cust
    const float* W1l_r1 = (const float*)d_in[4];
    const float* b1_r1  = (const float*)d_in[5];
    const float* W1r_r1 = (const float*)d_in[6];
    const float* W1l_r2 = (const float*)d_in[7];
    const float* b1_r2  = (const float*)d_in[8];
    const float* W1r_r2 = (const float*)d_in[9];
    const float* W2l_r1 = (const float*)d_in[10];
    const float* b2_r1  = (const float*)d_in[11];
    const float* W2r_r1 = (const float*)d_in[12];
    const float* Wlin  = (const float*)d_in[16];
    const float* blin  = (const float*)d_in[17];
    float* out = (float*)d_out;

    const int NC = in_sizes[0] / 64;
    const int NP = in_sizes[1] / 64;
    const int E  = in_sizes[2] / 2;
    const int nbP = (NP + BSZ - 1) >> BB;
    const int nbC = (NC + BSZ - 1) >> BB;

    // ---- workspace layout ----
    char* w = (char*)d_ws;
    int* gcur_p = (int*)w;  w += NBMAX * 4;     // zeroed together
    int* gcur_c = (int*)w;  w += NBMAX * 4;
    float* hconst = (float*)w; w += 68 * 4;
    w = (char*)(((uintptr_t)w + 255) & ~(uintptr_t)255);
    unsigned int* P_p = (unsigned int*)w;  w += (size_t)nbP * CAP * 4;
    unsigned int* P_c = (unsigned int*)w;  w += (size_t)nbC * CAP * 4;
    int* ss_p = (int*)w;    w += (size_t)nbP * CAP * 4;
    int* ss_c = (int*)w;    w += (size_t)nbC * CAP * 4;
    int* ro_p = (int*)w;    w += (size_t)NP * 4;
    int* ro_c = (int*)w;    w += (size_t)NC * 4;
    int* dg_p = (int*)w;    w += (size_t)NP * 4;
    int* dg_c = (int*)w;    w += (size_t)NC * 4;
    w = (char*)(((uintptr_t)w + 255) & ~(uintptr_t)255);
    _Float16* y_c = (_Float16*)w; w += (size_t)NC * 32 * 2;
    _Float16* y_p = (_Float16*)w; w += (size_t)NP * 32 * 2;
    _Float16* s_p = (_Float16*)w; w += (size_t)NP * 32 * 2;  // xp @ W1r_r1
    _Float16* s_c = (_Float16*)w; w += (size_t)NC * 32 * 2;  // xc @ W1r_r2
    w = (char*)(((uintptr_t)w + 255) & ~(uintptr_t)255);
    float* t_c = (float*)w; w += (size_t)NC * 4;
    float* u_p = (float*)w; w += (size_t)NP * 4;

    const int bprB = (E + 8191) / 8192;

    // 1. init: zero cursors (block 0) + head constants (block 1)
    kinit<<<2, 256, 0, stream>>>((int4*)gcur_p, 2 * NBMAX / 4,
                                 W2l_r1, W2r_r1, b2_r1, Wlin, blin, hconst);

    // 2-3. bucket build: bin (atomic-cursor regions) -> per-bucket sort
    kbin<<<2 * bprB, 512, 0, stream>>>(e_c2p, e_p2c, E, gcur_p, gcur_c, P_p, P_c, bprB);
    kbsort<<<nbP + nbC, 512, 0, stream>>>(P_p, P_c, gcur_p, gcur_c,
                                          ss_p, ss_c, ro_p, ro_c, dg_p, dg_c,
                                          NP, NC, nbP);

    // 4. LDS-tiled fused projections (y fp16 + s fp16; both node types)
    const int tblocksC = (NC + 127) / 128;
    const int tblocksP = (NP + 127) / 128;
    proj_tile<<<tblocksC + tblocksP, 256, 0, stream>>>(
        xc, W1l_r1, W1r_r2, y_c, s_c, NC, tblocksC,
        xp, W1l_r2, W1r_r1, y_p, s_p, NP);

    // 5. merged layer-1 pulls + scalar head collapse (writes t_c, u_p only)
    const int blocksP = (NP * 32 + 255) / 256;
    const int blocksC = (NC * 32 + 255) / 256;
    pull_l1_both<<<blocksP + blocksC, 256, 0, stream>>>(
        ro_p, dg_p, ss_p, y_c, s_p, b1_r1, hconst, u_p, NP, blocksP,
        ro_c, dg_c, ss_c, y_p, s_c, b1_r2, t_c, NC);

    // 6. layer-2 scalar pull + sigmoid (4B gathers from 400KB table)
    pull_l2_scalar<<<(NP * 4 + 255) / 256, 256, 0, stream>>>(
        ro_p, dg_p, ss_p, t_c, u_p, hconst, out, NP);
}

// Round 12
// 251.031 us; speedup vs baseline: 6.4123x; 6.4123x over previous
//
#include <hip/hip_runtime.h>
#include <stdint.h>

#define BB 8            // bucket = dst >> 8 (256 dsts per bucket)
#define BSZ 256
#define NBMAX 512       // max buckets per relation (100000>>8 = 391)
#define CAP 6144        // bucket edge capacity (mean ~4096, ~32 sigma margin)

typedef _Float16 half8 __attribute__((ext_vector_type(8)));

// ---------------------------------------------------------------------------
// init: block 0 zeroes bucket cursors; block 1 computes head constants
// (v2l = W2l@Wlin, v2r = W2r@Wlin, cbias = b2.Wlin + blin).
__global__ void kinit(int4* __restrict__ gcur, int n4,
                      const float* __restrict__ W2l, const float* __restrict__ W2r,
                      const float* __restrict__ b2, const float* __restrict__ Wlin,
                      const float* __restrict__ blin, float* __restrict__ hconst) {
    if (blockIdx.x == 0) {
        for (int i = threadIdx.x; i < n4; i += 256) gcur[i] = make_int4(0, 0, 0, 0);
    } else {
        int t = threadIdx.x;
        if (t < 64) {
            const float* W = (t < 32) ? W2l : W2r;
            int k = t & 31;
            float acc = 0.0f;
#pragma unroll
            for (int j = 0; j < 32; j++) acc += W[k * 32 + j] * Wlin[j];
            hconst[t] = acc;
        }
        if (t == 64) {
            float acc = blin[0];
#pragma unroll
            for (int j = 0; j < 32; j++) acc += b2[j] * Wlin[j];
            hconst[64] = acc;
        }
    }
}

// ---------------------------------------------------------------------------
// K1: bin edges into fixed-capacity bucket regions P[b*CAP + slot], slots
// claimed via global atomic cursors. 512 thr x 16 edges = 8192 edges/block.
// Packed: (src<<8 | dst&255).
__global__ void kbin(const int* __restrict__ e1, const int* __restrict__ e2, int E,
                     int* __restrict__ gcur1, int* __restrict__ gcur2,
                     unsigned int* __restrict__ P1, unsigned int* __restrict__ P2,
                     int blocksPerRel) {
    int rel = blockIdx.x >= blocksPerRel;
    int blk = rel ? blockIdx.x - blocksPerRel : blockIdx.x;
    const int* edge = rel ? e2 : e1;
    int* gcur = rel ? gcur2 : gcur1;
    unsigned int* P = rel ? P2 : P1;
    __shared__ int cnt[NBMAX];
    __shared__ int base[NBMAX];
    for (int i = threadIdx.x; i < NBMAX; i += 512) cnt[i] = 0;
    __syncthreads();
    int cbase = blk * 8192;
    int src[16], dst[16], rk[16];
#pragma unroll
    for (int k = 0; k < 16; k++) {
        int i = cbase + k * 512 + threadIdx.x;
        if (i < E) {
            src[k] = edge[i];
            dst[k] = edge[E + i];
            rk[k] = atomicAdd(&cnt[dst[k] >> BB], 1);
        }
    }
    __syncthreads();
    for (int b = threadIdx.x; b < NBMAX; b += 512)
        base[b] = cnt[b] ? atomicAdd(&gcur[b], cnt[b]) : 0;
    __syncthreads();
#pragma unroll
    for (int k = 0; k < 16; k++) {
        int i = cbase + k * 512 + threadIdx.x;
        if (i < E) {
            int b = dst[k] >> BB;
            int slot = base[b] + rk[k];
            if (slot < CAP)
                P[(size_t)b * CAP + slot] =
                    ((unsigned)src[k] << BB) | (unsigned)(dst[k] & (BSZ - 1));
        }
    }
}

// ---------------------------------------------------------------------------
// K2: per-bucket counting sort in LDS -> sorted srcs (bucket-strided ss)
// + per-node start (ro, absolute into ss) + degree (dg).
__global__ void kbsort(const unsigned int* __restrict__ P1, const unsigned int* __restrict__ P2,
                       const int* __restrict__ gcur1, const int* __restrict__ gcur2,
                       int* __restrict__ ss1, int* __restrict__ ss2,
                       int* __restrict__ ro1, int* __restrict__ ro2,
                       int* __restrict__ dg1, int* __restrict__ dg2,
                       int n1, int n2, int nb1) {
    int rel = blockIdx.x >= nb1;
    int b = rel ? blockIdx.x - nb1 : blockIdx.x;
    const unsigned int* P = (rel ? P2 : P1) + (size_t)b * CAP;
    int m = min((rel ? gcur2 : gcur1)[b], CAP);
    int* ss = (rel ? ss2 : ss1) + (size_t)b * CAP;
    int* ro = rel ? ro2 : ro1;
    int* dg = rel ? dg2 : dg1;
    int N = rel ? n2 : n1;

    __shared__ int cnt[BSZ];
    __shared__ int cur[BSZ];
    __shared__ int wsum[4];
    __shared__ int stage[CAP];

    int d0 = b << BB;
    int nd = min(BSZ, N - d0);
    int tid = threadIdx.x;

    if (tid < BSZ) cnt[tid] = 0;
    __syncthreads();
    for (int i = tid; i < m; i += 512) atomicAdd(&cnt[P[i] & (BSZ - 1)], 1);
    __syncthreads();
    int lane = tid & 63, wid = tid >> 6;
    int v = 0, sc = 0;
    if (tid < BSZ) {
        v = cnt[tid]; sc = v;
#pragma unroll
        for (int off = 1; off < 64; off <<= 1) {
            int t = __shfl_up(sc, off, 64);
            if (lane >= off) sc += t;
        }
        if (lane == 63) wsum[wid] = sc;
    }
    __syncthreads();
    if (tid < BSZ) {
        int woff = 0;
        for (int w = 0; w < wid; w++) woff += wsum[w];
        int excl = woff + sc - v;
        cur[tid] = excl;
        if (tid < nd) {
            ro[d0 + tid] = b * CAP + excl;
            dg[d0 + tid] = v;
        }
    }
    __syncthreads();
    for (int i = tid; i < m; i += 512) {
        unsigned int p = P[i];
        int slot = atomicAdd(&cur[p & (BSZ - 1)], 1);
        stage[slot] = (int)(p >> BB);
    }
    __syncthreads();
    for (int i = tid; i < m; i += 512) ss[i] = stage[i];
}

// ---------------------------------------------------------------------------
// LDS-tiled fused projection: block handles 64 nodes, 1 node/thread (36 VGPR
// — the 2-node variant spilled to scratch: R11 post-mortem, 4.1GB HBM traffic).
// Thread = (node, od-group of 8); computes y=x@Wy (fp16) and s=x@Ws (fp16).
__global__ void proj_tile(
    const float* __restrict__ x1, const float* __restrict__ Wy1, const float* __restrict__ Ws1,
    _Float16* __restrict__ y1, _Float16* __restrict__ s1, int N1, int blocks1,
    const float* __restrict__ x2, const float* __restrict__ Wy2, const float* __restrict__ Ws2,
    _Float16* __restrict__ y2, _Float16* __restrict__ s2, int N2) {
    int rel = blockIdx.x >= blocks1;
    int blk = rel ? blockIdx.x - blocks1 : blockIdx.x;
    const float* x = rel ? x2 : x1;
    const float* Wy = rel ? Wy2 : Wy1;
    const float* Ws = rel ? Ws2 : Ws1;
    _Float16* y = rel ? y2 : y1;
    _Float16* s = rel ? s2 : s1;
    int N = rel ? N2 : N1;

    __shared__ float xs[64][68];
    __shared__ float wyl[64][32];
    __shared__ float wsl[64][32];

    int tid = threadIdx.x;
    {
        const float4* a = (const float4*)Wy;
        const float4* b = (const float4*)Ws;
        float4* la = (float4*)&wyl[0][0];
        float4* lb = (float4*)&wsl[0][0];
        la[tid] = a[tid];
        la[tid + 256] = a[tid + 256];
        lb[tid] = b[tid];
        lb[tid + 256] = b[tid + 256];
    }
    int base = blk << 6;
#pragma unroll
    for (int i = 0; i < 4; i++) {
        int idx = i * 256 + tid;
        int row = idx >> 4, c4 = (idx & 15) << 2;
        int node = base + row;
        float4 v = (node < N) ? *(const float4*)(x + ((size_t)node << 6) + c4)
                              : make_float4(0.f, 0.f, 0.f, 0.f);
        *(float4*)&xs[row][c4] = v;
    }
    __syncthreads();

    int node = tid & 63;
    int ob = (tid >> 6) << 3;
    float ay[8] = {0,0,0,0,0,0,0,0};
    float as_[8] = {0,0,0,0,0,0,0,0};
#pragma unroll
    for (int kc = 0; kc < 16; kc++) {
        float4 xv = *(float4*)&xs[node][kc << 2];
#pragma unroll
        for (int kk = 0; kk < 4; kk++) {
            int k = (kc << 2) + kk;
            float xk = (kk == 0) ? xv.x : (kk == 1) ? xv.y : (kk == 2) ? xv.z : xv.w;
            float4 a = *(float4*)&wyl[k][ob];
            float4 b = *(float4*)&wyl[k][ob + 4];
            float4 c = *(float4*)&wsl[k][ob];
            float4 d = *(float4*)&wsl[k][ob + 4];
            ay[0] += xk * a.x; ay[1] += xk * a.y; ay[2] += xk * a.z; ay[3] += xk * a.w;
            ay[4] += xk * b.x; ay[5] += xk * b.y; ay[6] += xk * b.z; ay[7] += xk * b.w;
            as_[0] += xk * c.x; as_[1] += xk * c.y; as_[2] += xk * c.z; as_[3] += xk * c.w;
            as_[4] += xk * d.x; as_[5] += xk * d.y; as_[6] += xk * d.z; as_[7] += xk * d.w;
        }
    }
    int ng = base + node;
    if (ng < N) {
        union { _Float16 h[8]; uint4 v; } uy, us;
#pragma unroll
        for (int j = 0; j < 8; j++) { uy.h[j] = (_Float16)ay[j]; us.h[j] = (_Float16)as_[j]; }
        *(uint4*)(y + ((size_t)ng << 5) + ob) = uy.v;
        *(uint4*)(s + ((size_t)ng << 5) + ob) = us.v;
    }
}

// ---------------------------------------------------------------------------
// merged layer-1 pull (both relations), packed-fp16 accumulation:
// 32-lane group per node; 4 lanes/edge x 16B uint4 (8 fp16), 8 edges/iter,
// half8 acc (v_pk_add_f16), uint4 shuffle reduction. h never materialized:
// tgt[node] = relu(b + s + mean_gather(y)) . v2
__global__ void pull_l1_both(
    const int* __restrict__ ro_p, const int* __restrict__ dg_p, const int* __restrict__ ssp,
    const _Float16* __restrict__ y_c, const _Float16* __restrict__ sp,
    const float* __restrict__ b_p, const float* __restrict__ hconst,
    float* __restrict__ u_p, int NP, int blocksP,
    const int* __restrict__ ro_c, const int* __restrict__ dg_c, const int* __restrict__ ssc,
    const _Float16* __restrict__ y_p, const _Float16* __restrict__ sc_,
    const float* __restrict__ b_c, float* __restrict__ t_c, int NC) {
    int rel = blockIdx.x >= blocksP;
    int blk = rel ? blockIdx.x - blocksP : blockIdx.x;
    const int* ro = rel ? ro_c : ro_p;
    const int* dg = rel ? dg_c : dg_p;
    const int* ss = rel ? ssc : ssp;
    const _Float16* y = rel ? y_p : y_c;
    const _Float16* sf = rel ? sc_ : sp;
    const float* bv = rel ? b_c : b_p;
    const float* v2 = rel ? hconst : hconst + 32;  // t_c:v2l, u_p:v2r
    float* tgt = rel ? t_c : u_p;
    int N = rel ? NC : NP;

    int gid = blk * 256 + threadIdx.x;
    int node = gid >> 5, l = gid & 31;
    if (node >= N) return;
    int el = l >> 2, sub = l & 3;
    int start = ro[node], deg = dg[node];

    union U { uint4 v; half8 h; };
    half8 acc8 = (half8)(_Float16)0;
    for (int base = 0; base < deg; base += 16) {
        int j0 = base + el, j1 = base + 8 + el;
        bool v0 = j0 < deg, v1 = j1 < deg;
        int s0 = v0 ? ss[start + j0] : 0;
        int s1 = v1 ? ss[start + j1] : 0;
        U q0, q1;
        if (v0) q0.v = *(const uint4*)(y + ((size_t)s0 << 5) + (sub << 3));
        if (v1) q1.v = *(const uint4*)(y + ((size_t)s1 << 5) + (sub << 3));
        if (v0) acc8 += q0.h;
        if (v1) acc8 += q1.h;
    }
    // reduce over the 8 edge-lanes (xor 4,8,16) with packed adds
#pragma unroll
    for (int off = 4; off <= 16; off <<= 1) {
        U t, r;
        t.h = acc8;
        r.v.x = __shfl_xor(t.v.x, off, 32);
        r.v.y = __shfl_xor(t.v.y, off, 32);
        r.v.z = __shfl_xor(t.v.z, off, 32);
        r.v.w = __shfl_xor(t.v.w, off, 32);
        acc8 += r.h;
    }

    float invd = 1.0f / fmaxf((float)deg, 1.0f);
    union { uint4 v; _Float16 h[8]; } us;
    us.v = *(const uint4*)(sf + ((size_t)node << 5) + (sub << 3));
    float4 b0 = *(const float4*)(bv + (sub << 3));
    float4 b1 = *(const float4*)(bv + (sub << 3) + 4);
    float4 w0 = *(const float4*)(v2 + (sub << 3));
    float4 w1 = *(const float4*)(v2 + (sub << 3) + 4);
    float bb[8] = {b0.x, b0.y, b0.z, b0.w, b1.x, b1.y, b1.z, b1.w};
    float ww[8] = {w0.x, w0.y, w0.z, w0.w, w1.x, w1.y, w1.z, w1.w};
    float p = 0.0f;
#pragma unroll
    for (int j = 0; j < 8; j++) {
        float r = bb[j] + (float)us.h[j] + (float)acc8[j] * invd;
        p += fmaxf(r, 0.0f) * ww[j];
    }
    p += __shfl_xor(p, 1, 32);
    p += __shfl_xor(p, 2, 32);
    if (l == 0) tgt[node] = p;
}

// ---------------------------------------------------------------------------
// layer-2 scalar pull: logit = mean_{src in N(node)} t_c[src] + u_p[node]+cbias
__global__ void pull_l2_scalar(const int* __restrict__ ro, const int* __restrict__ dg,
                               const int* __restrict__ ss,
                               const float* __restrict__ t_c, const float* __restrict__ u_p,
                               const float* __restrict__ hconst,
                               float* __restrict__ out, int N) {
    int gid = blockIdx.x * blockDim.x + threadIdx.x;
    int node = gid >> 2, ln = gid & 3;
    if (node >= N) return;
    int s = ro[node], deg = dg[node], e = s + deg;
    float acc = 0.0f;
    for (int j = s + ln; j < e; j += 4) acc += t_c[ss[j]];
    acc += __shfl_xor(acc, 1, 4);
    acc += __shfl_xor(acc, 2, 4);
    if (ln == 0) {
        float logit = acc / fmaxf((float)deg, 1.0f) + u_p[node] + hconst[64];
        out[node] = 1.0f / (1.0f + expf(-logit));
    }
}

// ---------------------------------------------------------------------------
extern "C" void kernel_launch(void* const* d_in, const int* in_sizes, int n_in,
                              void* d_out, int out_size, void* d_ws, size_t ws_size,
                              hipStream_t stream) {
    const float* xc    = (const float*)d_in[0];
    const float* xp    = (const float*)d_in[1];
    const int*   e_c2p = (const int*)d_in[2];   // src=cust, dst=prod
    const int*   e_p2c = (const int*)d_in[3];   // src=prod, dst=cust
    const float* W1l_r1 = (const float*)d_in[4];
    const float* b1_r1  = (const float*)d_in[5];
    const float* W1r_r1 = (const float*)d_in[6];
    const float* W1l_r2 = (const float*)d_in[7];
    const float* b1_r2  = (const float*)d_in[8];
    const float* W1r_r2 = (const float*)d_in[9];
    const float* W2l_r1 = (const float*)d_in[10];
    const float* b2_r1  = (const float*)d_in[11];
    const float* W2r_r1 = (const float*)d_in[12];
    const float* Wlin  = (const float*)d_in[16];
    const float* blin  = (const float*)d_in[17];
    float* out = (float*)d_out;

    const int NC = in_sizes[0] / 64;
    const int NP = in_sizes[1] / 64;
    const int E  = in_sizes[2] / 2;
    const int nbP = (NP + BSZ - 1) >> BB;
    const int nbC = (NC + BSZ - 1) >> BB;

    // ---- workspace layout ----
    char* w = (char*)d_ws;
    int* gcur_p = (int*)w;  w += NBMAX * 4;     // zeroed together
    int* gcur_c = (int*)w;  w += NBMAX * 4;
    float* hconst = (float*)w; w += 68 * 4;
    w = (char*)(((uintptr_t)w + 255) & ~(uintptr_t)255);
    unsigned int* P_p = (unsigned int*)w;  w += (size_t)nbP * CAP * 4;
    unsigned int* P_c = (unsigned int*)w;  w += (size_t)nbC * CAP * 4;
    int* ss_p = (int*)w;    w += (size_t)nbP * CAP * 4;
    int* ss_c = (int*)w;    w += (size_t)nbC * CAP * 4;
    int* ro_p = (int*)w;    w += (size_t)NP * 4;
    int* ro_c = (int*)w;    w += (size_t)NC * 4;
    int* dg_p = (int*)w;    w += (size_t)NP * 4;
    int* dg_c = (int*)w;    w += (size_t)NC * 4;
    w = (char*)(((uintptr_t)w + 255) & ~(uintptr_t)255);
    _Float16* y_c = (_Float16*)w; w += (size_t)NC * 32 * 2;
    _Float16* y_p = (_Float16*)w; w += (size_t)NP * 32 * 2;
    _Float16* s_p = (_Float16*)w; w += (size_t)NP * 32 * 2;  // xp @ W1r_r1
    _Float16* s_c = (_Float16*)w; w += (size_t)NC * 32 * 2;  // xc @ W1r_r2
    w = (char*)(((uintptr_t)w + 255) & ~(uintptr_t)255);
    float* t_c = (float*)w; w += (size_t)NC * 4;
    float* u_p = (float*)w; w += (size_t)NP * 4;

    const int bprB = (E + 8191) / 8192;

    // 1. init: zero cursors (block 0) + head constants (block 1)
    kinit<<<2, 256, 0, stream>>>((int4*)gcur_p, 2 * NBMAX / 4,
                                 W2l_r1, W2r_r1, b2_r1, Wlin, blin, hconst);

    // 2-3. bucket build: bin (atomic-cursor regions) -> per-bucket sort
    kbin<<<2 * bprB, 512, 0, stream>>>(e_c2p, e_p2c, E, gcur_p, gcur_c, P_p, P_c, bprB);
    kbsort<<<nbP + nbC, 512, 0, stream>>>(P_p, P_c, gcur_p, gcur_c,
                                          ss_p, ss_c, ro_p, ro_c, dg_p, dg_c,
                                          NP, NC, nbP);

    // 4. LDS-tiled fused projections (y fp16 + s fp16; both node types)
    const int tblocksC = (NC + 63) / 64;
    const int tblocksP = (NP + 63) / 64;
    proj_tile<<<tblocksC + tblocksP, 256, 0, stream>>>(
        xc, W1l_r1, W1r_r2, y_c, s_c, NC, tblocksC,
        xp, W1l_r2, W1r_r1, y_p, s_p, NP);

    // 5. merged layer-1 pulls + scalar head collapse (writes t_c, u_p only)
    const int blocksP = (NP * 32 + 255) / 256;
    const int blocksC = (NC * 32 + 255) / 256;
    pull_l1_both<<<blocksP + blocksC, 256, 0, stream>>>(
        ro_p, dg_p, ss_p, y_c, s_p, b1_r1, hconst, u_p, NP, blocksP,
        ro_c, dg_c, ss_c, y_p, s_c, b1_r2, t_c, NC);

    // 6. layer-2 scalar pull + sigmoid (4B gathers from 400KB table)
    pull_l2_scalar<<<(NP * 4 + 255) / 256, 256, 0, stream>>>(
        ro_p, dg_p, ss_p, t_c, u_p, hconst, out, NP);
}